// Round 1
// baseline (144.360 us; speedup 1.0000x reference)
//
#include <hip/hip_runtime.h>
#include <hip/hip_bf16.h>
#include <math.h>

// Problem constants (from reference): T=4096, B=64, D=64, SCALE = 1/8.
#define T_DIM 4096
#define B_DIM 64
#define D_DIM 64
#define NROWS (T_DIM * B_DIM)   // 262144 (t,b) rows, each 64 floats

// Workspace layout (float offsets)
#define WS_M     0        // 64x64 = 4096 floats: M[d][d'] = sum_o Wq[o,d]*Wk[o,d']
#define WS_W     4096     // 64: w[d]  = sum_o Wq[o,d]*bk[o]
#define WS_U     4160     // 64: u[d'] = sum_o bq[o]*Wk[o,d']
#define WS_C     4224     // 1:  c     = bq.bk
#define WS_MX    4288     // 64: per-b score max
#define WS_INV   4352     // 64: per-b 1/sum(exp)
#define WS_SCORE 8192     // [B][T] = 262144 floats

// ---------------------------------------------------------------------------
// K1: precompute bilinear-form constants. Tiny.
__global__ __launch_bounds__(64) void k1_precompute(
    const float* __restrict__ Wq, const float* __restrict__ bq,
    const float* __restrict__ Wk, const float* __restrict__ bk,
    float* __restrict__ ws) {
  const int tid = threadIdx.x;
  const int blk = blockIdx.x;
  if (blk < 64) {
    const int d = blk;
    float acc = 0.f;
    for (int o = 0; o < 64; ++o)
      acc = fmaf(Wq[o * 64 + d], Wk[o * 64 + tid], acc);
    ws[WS_M + d * 64 + tid] = acc;
  } else {
    float uacc = 0.f, wacc = 0.f, cacc = 0.f;
    for (int o = 0; o < 64; ++o) {
      uacc = fmaf(bq[o], Wk[o * 64 + tid], uacc);
      wacc = fmaf(Wq[o * 64 + tid], bk[o], wacc);
      cacc = fmaf(bq[o], bk[o], cacc);
    }
    ws[WS_U + tid] = uacc;
    ws[WS_W + tid] = wacc;
    if (tid == 0) ws[WS_C] = cacc;
  }
}

// ---------------------------------------------------------------------------
// K2: score[b][t] = SCALE * (e^T M f + w.e + u.f + c), one wave per row.
// Lane d owns M row d in VGPRs; f is broadcast through a wave-private LDS slice.
__global__ __launch_bounds__(256, 4) void k2_score(
    const float* __restrict__ eeg, const float* __restrict__ fnirs,
    float* __restrict__ ws) {
  __shared__ float fbuf[4][64];
  const int lane = threadIdx.x & 63;
  const int wv = threadIdx.x >> 6;
  const int wave = blockIdx.x * 4 + wv;
  const int nwaves = gridDim.x * 4;

  // M row for this lane (64 VGPRs), amortized over ~64 rows per wave.
  float Mrow[64];
  const float4* M4 = reinterpret_cast<const float4*>(ws + WS_M) + lane * 16;
#pragma unroll
  for (int j = 0; j < 16; ++j) {
    const float4 m = M4[j];
    Mrow[4 * j + 0] = m.x; Mrow[4 * j + 1] = m.y;
    Mrow[4 * j + 2] = m.z; Mrow[4 * j + 3] = m.w;
  }
  const float wd = ws[WS_W + lane];
  const float ud = ws[WS_U + lane];
  const float cb = ws[WS_C];
  float* __restrict__ score = ws + WS_SCORE;

  for (int row = wave; row < NROWS; row += nwaves) {
    const float e = eeg[row * 64 + lane];    // coalesced 256B / wave
    const float f = fnirs[row * 64 + lane];
    fbuf[wv][lane] = f;                      // wave-private slice, no barrier
    const float4* fb = reinterpret_cast<const float4*>(&fbuf[wv][0]);
    float r0 = 0.f, r1 = 0.f, r2 = 0.f, r3 = 0.f;
#pragma unroll
    for (int j = 0; j < 16; ++j) {
      const float4 fj = fb[j];               // uniform address -> broadcast
      r0 = fmaf(Mrow[4 * j + 0], fj.x, r0);
      r1 = fmaf(Mrow[4 * j + 1], fj.y, r1);
      r2 = fmaf(Mrow[4 * j + 2], fj.z, r2);
      r3 = fmaf(Mrow[4 * j + 3], fj.w, r3);
    }
    float contrib = e * (((r0 + r1) + (r2 + r3)) + wd) + ud * f;
#pragma unroll
    for (int off = 32; off > 0; off >>= 1)
      contrib += __shfl_xor(contrib, off, 64);
    if (lane == 0) {
      const int b = row & 63;
      const int t = row >> 6;
      score[b * T_DIM + t] = (contrib + cb) * 0.125f;
    }
  }
}

// ---------------------------------------------------------------------------
// K3: per-b softmax stats over T=4096 scores. 64 blocks x 256 threads.
__global__ __launch_bounds__(256) void k3_softmax_stats(float* __restrict__ ws) {
  __shared__ float red[8];
  const int b = blockIdx.x;
  const int tid = threadIdx.x;
  const float* __restrict__ score = ws + WS_SCORE + b * T_DIM;

  float vals[16];
  float m = -1e30f;
#pragma unroll
  for (int k = 0; k < 16; ++k) {
    vals[k] = score[k * 256 + tid];
    m = fmaxf(m, vals[k]);
  }
#pragma unroll
  for (int off = 32; off > 0; off >>= 1)
    m = fmaxf(m, __shfl_xor(m, off, 64));
  if ((tid & 63) == 0) red[tid >> 6] = m;
  __syncthreads();
  m = fmaxf(fmaxf(red[0], red[1]), fmaxf(red[2], red[3]));

  float s = 0.f;
#pragma unroll
  for (int k = 0; k < 16; ++k) s += __expf(vals[k] - m);
#pragma unroll
  for (int off = 32; off > 0; off >>= 1)
    s += __shfl_xor(s, off, 64);
  if ((tid & 63) == 0) red[4 + (tid >> 6)] = s;
  __syncthreads();
  if (tid == 0) {
    const float tot = red[4] + red[5] + red[6] + red[7];
    ws[WS_MX + b] = m;
    ws[WS_INV + b] = 1.0f / tot;
  }
}

// ---------------------------------------------------------------------------
// K4: out = eeg + attn * (Wv f + bv). Lane d owns Wv row d in VGPRs.
__global__ __launch_bounds__(256, 4) void k4_output(
    const float* __restrict__ eeg, const float* __restrict__ fnirs,
    const float* __restrict__ Wv, const float* __restrict__ bv,
    const float* __restrict__ ws, float* __restrict__ out) {
  __shared__ float fbuf[4][64];
  const int lane = threadIdx.x & 63;
  const int wv = threadIdx.x >> 6;
  const int wave = blockIdx.x * 4 + wv;
  const int nwaves = gridDim.x * 4;

  float Vrow[64];
  const float4* V4 = reinterpret_cast<const float4*>(Wv) + lane * 16;
#pragma unroll
  for (int j = 0; j < 16; ++j) {
    const float4 m = V4[j];
    Vrow[4 * j + 0] = m.x; Vrow[4 * j + 1] = m.y;
    Vrow[4 * j + 2] = m.z; Vrow[4 * j + 3] = m.w;
  }
  const float bvd = bv[lane];
  const float* __restrict__ score = ws + WS_SCORE;

  for (int row = wave; row < NROWS; row += nwaves) {
    const float e = eeg[row * 64 + lane];
    const float f = fnirs[row * 64 + lane];
    fbuf[wv][lane] = f;
    const float4* fb = reinterpret_cast<const float4*>(&fbuf[wv][0]);
    float r0 = 0.f, r1 = 0.f, r2 = 0.f, r3 = 0.f;
#pragma unroll
    for (int j = 0; j < 16; ++j) {
      const float4 fj = fb[j];
      r0 = fmaf(Vrow[4 * j + 0], fj.x, r0);
      r1 = fmaf(Vrow[4 * j + 1], fj.y, r1);
      r2 = fmaf(Vrow[4 * j + 2], fj.z, r2);
      r3 = fmaf(Vrow[4 * j + 3], fj.w, r3);
    }
    const float v = ((r0 + r1) + (r2 + r3)) + bvd;
    const int b = row & 63;
    const int t = row >> 6;
    const float attn = __expf(score[b * T_DIM + t] - ws[WS_MX + b]) * ws[WS_INV + b];
    out[row * 64 + lane] = e + attn * v;   // coalesced 256B / wave
  }
}

// ---------------------------------------------------------------------------
extern "C" void kernel_launch(void* const* d_in, const int* in_sizes, int n_in,
                              void* d_out, int out_size, void* d_ws, size_t ws_size,
                              hipStream_t stream) {
  const float* eeg   = (const float*)d_in[0];
  const float* fnirs = (const float*)d_in[1];
  const float* Wq    = (const float*)d_in[2];
  const float* bq    = (const float*)d_in[3];
  const float* Wk    = (const float*)d_in[4];
  const float* bk    = (const float*)d_in[5];
  const float* Wv    = (const float*)d_in[6];
  const float* bv    = (const float*)d_in[7];
  float* out = (float*)d_out;
  float* ws  = (float*)d_ws;

  k1_precompute<<<65, 64, 0, stream>>>(Wq, bq, Wk, bk, ws);
  k2_score<<<1024, 256, 0, stream>>>(eeg, fnirs, ws);
  k3_softmax_stats<<<64, 256, 0, stream>>>(ws);
  k4_output<<<1024, 256, 0, stream>>>(eeg, fnirs, Wv, bv, ws, out);
}